// Round 4
// baseline (54.139 us; speedup 1.0000x reference)
//
#include <hip/hip_runtime.h>
#include <math.h>

#define MAP_SIZE 256
#define KV 64
#define TAU 6e-5f   // |cross| below this: tanh(1e5*cross) deviates from sign by >1.2e-5

// acos approx (Abramowitz & Stegun 4.4.45): |err| <= ~7e-5 rad
__device__ __forceinline__ float fast_acos(float x) {
    float a = __builtin_fabsf(x);
    float p = fmaf(fmaf(fmaf(-0.0187293f, a, 0.0742610f), a, -0.2121144f), a, 1.5707288f);
    float r = __builtin_amdgcn_sqrtf(1.0f - a) * p;
    return x >= 0.0f ? r : 3.14159274f - r;
}

__global__ void init_gmax(unsigned int* g) {
    if (threadIdx.x == 0) *g = 0u;
}

__global__ __launch_bounds__(256) void cdm_pass1(
    const float* __restrict__ contour,   // (bn, KV, 2)
    float* __restrict__ out,             // (bn, 256, 256) unnormalized prod
    unsigned int* __restrict__ gmax)     // global max accumulator (float bits)
{
    __shared__ float2 cv[KV];
    const int blocksPerImg = (MAP_SIZE * MAP_SIZE) / 256;  // 256
    const int bn  = blockIdx.x / blocksPerImg;
    const int pix = (blockIdx.x % blocksPerImg) * 256 + threadIdx.x;

    if (threadIdx.x < KV) {
        cv[threadIdx.x] = ((const float2*)contour)[bn * KV + threadIdx.x];
    }
    __syncthreads();

    const float mx = (float)(pix >> 8) * (1.0f / MAP_SIZE);
    const float my = (float)(pix & 255) * (1.0f / MAP_SIZE);

    // ---- FAST LOOP: integer winding (Sunday crossings) + min squared dist ----
    float dx = cv[0].x - mx, dy = cv[0].y - my;
    bool  pgt = dy > 0.0f;

    float mindd = 1e30f;
    int   wn = 0;
    bool  anyflag = false;

    #pragma unroll 16
    for (int k = 0; k < KV; ++k) {
        const float2 c = cv[(k + 1) & (KV - 1)];
        const float rx = c.x - mx;
        const float ry = c.y - my;
        const float rr = fmaf(rx, rx, ry * ry);
        mindd = fminf(mindd, rr);          // covers vertices 1..63,0 = all

        const float cross = fmaf(dy, rx, -dx * ry);
        const bool ngt = ry > 0.0f;

        wn += ((!pgt) & ngt & (cross <  0.0f)) ? 1 : 0;
        wn -= ((pgt) & (!ngt) & (cross >= 0.0f)) ? 1 : 0;

        anyflag |= (__builtin_fabsf(cross) < TAU);

        dx = rx; dy = ry; pgt = ngt;
    }

    // ---- RARE CORRECTION: wave-uniform branch (s_cbranch, not if-converted) ----
    float corr = 0.0f;
    if (__any(anyflag)) {
        float sdx = cv[0].x - mx, sdy = cv[0].y - my;
        #pragma unroll 1
        for (int k = 0; k < KV; ++k) {
            const float2 c = cv[(k + 1) & (KV - 1)];
            const float srx = c.x - mx;
            const float sry = c.y - my;
            const float cross = fmaf(sdy, srx, -sdx * sry);
            const float acr = __builtin_fabsf(cross);
            if (__any(acr < TAU)) {        // wave-uniform again
                const float sdd = fmaf(sdx, sdx, sdy * sdy);
                const float srr = fmaf(srx, srx, sry * sry);
                const float rsd = __builtin_amdgcn_rsqf(fmaxf(sdd, 1e-12f));
                const float rsr = __builtin_amdgcn_rsqf(fmaxf(srr, 1e-12f));
                const float dot = fmaf(sdx, srx, sdy * sry);
                float ca = dot * rsd * rsr;
                ca = fminf(fmaxf(ca, -1.0f + 1e-5f), 1.0f - 1e-5f);
                const float ang = fast_acos(ca);
                // tanh(K*cross) = 1 - 2/(exp2(2K*log2e*cross)+1)
                const float e  = __builtin_amdgcn_exp2f(cross * 288539.0083f);
                const float th = fmaf(-2.0f, __builtin_amdgcn_rcpf(e + 1.0f), 1.0f);
                const float s  = (cross >= 0.0f) ? 1.0f : -1.0f;
                corr = (acr < TAU) ? fmaf(th - s, ang, corr) : corr;
            }
            sdx = srx; sdy = sry;
        }
    }

    // S_ref = -2*pi*W + corr  ->  |S|/2pi = |corr/(2pi) - W|
    const float inv2pi = 0.15915494309189535f;
    const float resize = __builtin_fabsf(fmaf(corr, inv2pi, -(float)wn));
    const float prod = resize * __builtin_amdgcn_sqrtf(mindd);
    out[bn * (MAP_SIZE * MAP_SIZE) + pix] = prod;

    // block max reduction (prod >= 0 -> float bits compare as uint)
    float m = prod;
    #pragma unroll
    for (int off = 32; off > 0; off >>= 1)
        m = fmaxf(m, __shfl_xor(m, off));

    __shared__ float wmax[4];
    const int lane = threadIdx.x & 63;
    const int wid  = threadIdx.x >> 6;
    if (lane == 0) wmax[wid] = m;
    __syncthreads();
    if (threadIdx.x == 0) {
        const float bm = fmaxf(fmaxf(wmax[0], wmax[1]), fmaxf(wmax[2], wmax[3]));
        atomicMax(gmax, __float_as_uint(bm));
    }
}

__global__ __launch_bounds__(256) void cdm_pass2(
    float4* __restrict__ out, const unsigned int* __restrict__ gmax, int n4)
{
    const float inv = 1.0f / __uint_as_float(*gmax);
    const int i = blockIdx.x * 256 + threadIdx.x;
    if (i < n4) {
        float4 v = out[i];
        v.x *= inv; v.y *= inv; v.z *= inv; v.w *= inv;
        out[i] = v;
    }
}

extern "C" void kernel_launch(void* const* d_in, const int* in_sizes, int n_in,
                              void* d_out, int out_size, void* d_ws, size_t ws_size,
                              hipStream_t stream) {
    const float* contour = (const float*)d_in[0];
    float* out = (float*)d_out;
    unsigned int* gmax = (unsigned int*)d_ws;

    const int bn = in_sizes[0] / (KV * 2);            // 8
    const int npix = bn * MAP_SIZE * MAP_SIZE;        // 524288 == out_size

    init_gmax<<<1, 64, 0, stream>>>(gmax);

    const int blocksPerImg = (MAP_SIZE * MAP_SIZE) / 256;
    cdm_pass1<<<bn * blocksPerImg, 256, 0, stream>>>(contour, out, gmax);

    const int n4 = npix / 4;
    cdm_pass2<<<(n4 + 255) / 256, 256, 0, stream>>>((float4*)out, gmax, n4);
}

// Round 5
// 37.086 us; speedup vs baseline: 1.4598x; 1.4598x over previous
//
#include <hip/hip_runtime.h>
#include <math.h>

#define MAP_SIZE 256
#define KV 64
#define PPT 4        // pixels per thread: same row, 4 consecutive columns
#define TAU 6e-5f    // |cross| below this: tanh(1e5*x) deviates from sign(x) by >1.2e-5
#define HPX (1.0f / MAP_SIZE)

// acos approx (Abramowitz & Stegun 4.4.45): |err| <= ~7e-5 rad
__device__ __forceinline__ float fast_acos(float x) {
    float a = __builtin_fabsf(x);
    float p = fmaf(fmaf(fmaf(-0.0187293f, a, 0.0742610f), a, -0.2121144f), a, 1.5707288f);
    float r = __builtin_amdgcn_sqrtf(1.0f - a) * p;
    return x >= 0.0f ? r : 3.14159274f - r;
}

__global__ void init_gmax(unsigned int* g) {
    if (threadIdx.x == 0) *g = 0u;
}

__global__ __launch_bounds__(256) void cdm_pass1(
    const float* __restrict__ contour,   // (bn, KV, 2)
    float* __restrict__ out,             // (bn, 256, 256) unnormalized prod
    unsigned int* __restrict__ gmax)
{
    __shared__ float4 cv4[KV / 2];       // vertex pairs (2j, 2j+1)
    const int blocksPerImg = (MAP_SIZE * MAP_SIZE) / (256 * PPT);  // 64
    const int bn = blockIdx.x / blocksPerImg;
    const int p0 = (blockIdx.x % blocksPerImg) * (256 * PPT) + threadIdx.x * PPT;

    if (threadIdx.x < KV / 2) {
        cv4[threadIdx.x] = ((const float4*)contour)[bn * (KV / 2) + threadIdx.x];
    }
    __syncthreads();

    const float mx  = (float)(p0 >> 8) * HPX;   // shared by all 4 pixels
    const float my0 = (float)(p0 & 255) * HPX;  // pixel i at my0 + i*HPX

    const float4 q0 = cv4[0];
    const float v0x = q0.x, v0y = q0.y;

    // carried: d = (current edge's A) - m. dx shared; dy_i = dy0 - i*HPX
    float dx  = v0x - mx;
    float dy0 = v0y - my0;

    float mindd[PPT];
    int   wn[PPT];
    bool  fl[PPT], pgt[PPT];
    #pragma unroll
    for (int i = 0; i < PPT; ++i) {
        mindd[i] = 1e30f; wn[i] = 0; fl[i] = false;
        pgt[i] = (dy0 - (float)i * HPX) > 0.0f;
    }

    // ---- FAST PATH: integer winding + min dist, 2 edges per ds_read_b128 ----
    auto edge = [&](float bx, float by) {
        const float rx  = bx - mx;              // shared
        const float rxx = rx * rx;              // shared
        const float ry0 = by - my0;             // shared
        const float ex  = rx - dx;              // = Bx - Ax (shared)
        const float cr0 = fmaf(dy0, rx, -dx * ry0);  // cross for pixel 0 (shared)
        #pragma unroll
        for (int i = 0; i < PPT; ++i) {
            const float iH = (float)i * HPX;
            const float ry = ry0 - iH;
            const float rr = fmaf(ry, ry, rxx);
            mindd[i] = fminf(mindd[i], rr);
            const float cr = fmaf(-iH, ex, cr0);
            const bool ngt = ry > 0.0f;
            wn[i] += ((!pgt[i]) & ngt & (cr <  0.0f)) ? 1 : 0;
            wn[i] -= ((pgt[i]) & (!ngt) & (cr >= 0.0f)) ? 1 : 0;
            fl[i] |= (__builtin_fabsf(cr) < TAU);
            pgt[i] = ngt;
        }
        dx = rx; dy0 = ry0;
    };

    edge(q0.z, q0.w);                   // edge v0 -> v1
    #pragma unroll 8
    for (int jj = 1; jj < KV / 2; ++jj) {
        const float4 t = cv4[jj];
        edge(t.x, t.y);                 // edge -> v(2jj)
        edge(t.z, t.w);                 // edge -> v(2jj+1)
    }
    edge(v0x, v0y);                     // wrap edge v63 -> v0

    // ---- RARE CORRECTION: wave-uniform gates, cheap cross-only rescan ----
    float corr[PPT] = {0.0f, 0.0f, 0.0f, 0.0f};
    if (__any(fl[0] | fl[1] | fl[2] | fl[3])) {
        float sdx  = v0x - mx;
        float sdy0 = v0y - my0;
        auto corrEdge = [&](float bx, float by) {
            const float rx  = bx - mx;
            const float ry0 = by - my0;
            const float ex  = rx - sdx;
            const float cr0 = fmaf(sdy0, rx, -sdx * ry0);
            float cr[PPT];
            bool hit = false;
            #pragma unroll
            for (int i = 0; i < PPT; ++i) {
                cr[i] = fmaf(-(float)i * HPX, ex, cr0);
                hit |= (__builtin_fabsf(cr[i]) < TAU);
            }
            if (__any(hit)) {
                #pragma unroll
                for (int i = 0; i < PPT; ++i) {
                    const float iH  = (float)i * HPX;
                    const float sdy = sdy0 - iH;
                    const float ry  = ry0 - iH;
                    const float sdd = fmaf(sdx, sdx, sdy * sdy);
                    const float srr = fmaf(rx, rx, ry * ry);
                    const float rsd = __builtin_amdgcn_rsqf(fmaxf(sdd, 1e-12f));
                    const float rsr = __builtin_amdgcn_rsqf(fmaxf(srr, 1e-12f));
                    const float dot = fmaf(sdx, rx, sdy * ry);
                    float ca = dot * rsd * rsr;
                    ca = fminf(fmaxf(ca, -1.0f + 1e-5f), 1.0f - 1e-5f);
                    const float ang = fast_acos(ca);
                    const float e   = __builtin_amdgcn_exp2f(cr[i] * 288539.0083f);
                    const float th  = fmaf(-2.0f, __builtin_amdgcn_rcpf(e + 1.0f), 1.0f);
                    const float s   = (cr[i] >= 0.0f) ? 1.0f : -1.0f;
                    corr[i] = (__builtin_fabsf(cr[i]) < TAU) ? fmaf(th - s, ang, corr[i]) : corr[i];
                }
            }
            sdx = rx; sdy0 = ry0;
        };
        corrEdge(q0.z, q0.w);
        #pragma unroll 1
        for (int jj = 1; jj < KV / 2; ++jj) {
            const float4 t = cv4[jj];
            corrEdge(t.x, t.y);
            corrEdge(t.z, t.w);
        }
        corrEdge(v0x, v0y);
    }

    // S_ref = -2*pi*W + corr  ->  |S|/2pi = |corr/(2pi) - W|
    const float inv2pi = 0.15915494309189535f;
    float pr[PPT];
    #pragma unroll
    for (int i = 0; i < PPT; ++i) {
        const float resize = __builtin_fabsf(fmaf(corr[i], inv2pi, -(float)wn[i]));
        pr[i] = resize * __builtin_amdgcn_sqrtf(mindd[i]);
    }

    const int gp = bn * (MAP_SIZE * MAP_SIZE) + p0;
    *(float4*)(out + gp) = make_float4(pr[0], pr[1], pr[2], pr[3]);

    // block max reduction (prod >= 0 -> float bits compare as uint)
    float m = fmaxf(fmaxf(pr[0], pr[1]), fmaxf(pr[2], pr[3]));
    #pragma unroll
    for (int off = 32; off > 0; off >>= 1)
        m = fmaxf(m, __shfl_xor(m, off));

    __shared__ float wmax[4];
    const int lane = threadIdx.x & 63;
    const int wid  = threadIdx.x >> 6;
    if (lane == 0) wmax[wid] = m;
    __syncthreads();
    if (threadIdx.x == 0) {
        const float bm = fmaxf(fmaxf(wmax[0], wmax[1]), fmaxf(wmax[2], wmax[3]));
        atomicMax(gmax, __float_as_uint(bm));
    }
}

__global__ __launch_bounds__(256) void cdm_pass2(
    float4* __restrict__ out, const unsigned int* __restrict__ gmax, int n4)
{
    const float inv = 1.0f / __uint_as_float(*gmax);
    const int i = blockIdx.x * 256 + threadIdx.x;
    if (i < n4) {
        float4 v = out[i];
        v.x *= inv; v.y *= inv; v.z *= inv; v.w *= inv;
        out[i] = v;
    }
}

extern "C" void kernel_launch(void* const* d_in, const int* in_sizes, int n_in,
                              void* d_out, int out_size, void* d_ws, size_t ws_size,
                              hipStream_t stream) {
    const float* contour = (const float*)d_in[0];
    float* out = (float*)d_out;
    unsigned int* gmax = (unsigned int*)d_ws;

    const int bn = in_sizes[0] / (KV * 2);            // 8
    const int npix = bn * MAP_SIZE * MAP_SIZE;        // 524288 == out_size

    init_gmax<<<1, 64, 0, stream>>>(gmax);

    const int blocksPerImg = (MAP_SIZE * MAP_SIZE) / (256 * PPT);
    cdm_pass1<<<bn * blocksPerImg, 256, 0, stream>>>(contour, out, gmax);

    const int n4 = npix / 4;
    cdm_pass2<<<(n4 + 255) / 256, 256, 0, stream>>>((float4*)out, gmax, n4);
}

// Round 6
// 36.224 us; speedup vs baseline: 1.4946x; 1.0238x over previous
//
#include <hip/hip_runtime.h>
#include <math.h>

#define MAP_SIZE 256
#define KV 64
#define PPT 2                      // pixels per thread: consecutive y
#define HPX (1.0f / 256.0f)
#define TK 288539.0083f            // 2 * 100000 * log2(e)

__global__ __launch_bounds__(256) void cdm_pass1(
    const float* __restrict__ contour,   // (bn, KV, 2)
    float* __restrict__ out,             // (bn, 256, 256) unnormalized prod
    unsigned int* __restrict__ gmax)
{
    __shared__ float4 cv4[KV / 2];       // vertex pairs (2j, 2j+1)
    const int blocksPerImg = (MAP_SIZE * MAP_SIZE) / (256 * PPT);  // 128
    const int bn = blockIdx.x / blocksPerImg;
    const int p0 = (blockIdx.x % blocksPerImg) * (256 * PPT) + threadIdx.x * PPT;

    if (threadIdx.x < KV / 2)
        cv4[threadIdx.x] = ((const float4*)contour)[bn * (KV / 2) + threadIdx.x];
    __syncthreads();

    const float mx  = (float)(p0 >> 8) * HPX;   // shared by both pixels
    const float my0 = (float)(p0 & 255) * HPX;  // px1 at my0 + HPX

    const float4 q0 = cv4[0];
    float ax  = q0.x - mx;    // carried: A - m (x shared, y for px0)
    float ay0 = q0.y - my0;

    float mindd0 = 1e30f, mindd1 = 1e30f;
    float corr0 = 0.0f, corr1 = 0.0f;
    int   wn0 = 0, wn1 = 0;
    bool  pgt0 = ay0 > 0.0f;
    bool  pgt1 = (ay0 - HPX) > 0.0f;

    // One fused, branch-free pass over all 64 edges.
    // resize = |W + sum sg*d2*[dot<0]|,  d2 = 1/(exp(2K|cr|)+1)  (tanh deviation/2;
    // exp2->inf->rcp->0 kills it outside the band, pi cancels against 1/2pi).
    auto edge = [&](float bx, float by) {
        const float rx   = bx - mx;
        const float ry0  = by - my0;
        const float rxx  = rx * rx;
        const float dxrx = ax * rx;                 // shared part of dot
        const float ex   = rx - ax;                 // Bx - Ax
        const float cr0  = fmaf(ay0, rx, -ax * ry0);
        // ---- pixel 0 ----
        {
            const float ry = ry0;
            const float rr = fmaf(ry, ry, rxx);
            mindd0 = fminf(mindd0, rr);
            const float cr = cr0;
            const bool ngt = ry > 0.0f;
            wn0 += ((!pgt0) & ngt & (cr <  0.0f)) ? 1 : 0;
            wn0 -= ((pgt0) & (!ngt) & (cr >= 0.0f)) ? 1 : 0;
            const float e   = __builtin_amdgcn_exp2f(__builtin_fabsf(cr) * TK);
            const float d2  = __builtin_amdgcn_rcpf(e + 1.0f);
            const float dot = fmaf(ay0, ry, dxrx);
            const float t   = (dot < 0.0f) ? d2 : 0.0f;
            corr0 += (cr >= 0.0f) ? t : -t;
            pgt0 = ngt;
        }
        // ---- pixel 1 (y + HPX): cr1 = cr0 - HPX*ex ----
        {
            const float ry = ry0 - HPX;
            const float rr = fmaf(ry, ry, rxx);
            mindd1 = fminf(mindd1, rr);
            const float cr = fmaf(-HPX, ex, cr0);
            const bool ngt = ry > 0.0f;
            wn1 += ((!pgt1) & ngt & (cr <  0.0f)) ? 1 : 0;
            wn1 -= ((pgt1) & (!ngt) & (cr >= 0.0f)) ? 1 : 0;
            const float e   = __builtin_amdgcn_exp2f(__builtin_fabsf(cr) * TK);
            const float d2  = __builtin_amdgcn_rcpf(e + 1.0f);
            const float dot = fmaf(ay0 - HPX, ry, dxrx);
            const float t   = (dot < 0.0f) ? d2 : 0.0f;
            corr1 += (cr >= 0.0f) ? t : -t;
            pgt1 = ngt;
        }
        ax = rx; ay0 = ry0;
    };

    edge(q0.z, q0.w);                   // v0 -> v1
    #pragma unroll 4
    for (int jj = 1; jj < KV / 2; ++jj) {
        const float4 t = cv4[jj];
        edge(t.x, t.y);                 // -> v(2jj)
        edge(t.z, t.w);                 // -> v(2jj+1)
    }
    edge(q0.x, q0.y);                   // wrap v63 -> v0

    const float r0 = __builtin_fabsf((float)wn0 + corr0);
    const float r1 = __builtin_fabsf((float)wn1 + corr1);
    const float pv0 = r0 * __builtin_amdgcn_sqrtf(mindd0);
    const float pv1 = r1 * __builtin_amdgcn_sqrtf(mindd1);

    *(float2*)(out + bn * (MAP_SIZE * MAP_SIZE) + p0) = make_float2(pv0, pv1);

    // block max reduction (values >= 0 -> float bits compare as uint)
    float m = fmaxf(pv0, pv1);
    #pragma unroll
    for (int off = 32; off > 0; off >>= 1)
        m = fmaxf(m, __shfl_xor(m, off));

    __shared__ float wmax[4];
    const int lane = threadIdx.x & 63;
    const int wid  = threadIdx.x >> 6;
    if (lane == 0) wmax[wid] = m;
    __syncthreads();
    if (threadIdx.x == 0) {
        const float bm = fmaxf(fmaxf(wmax[0], wmax[1]), fmaxf(wmax[2], wmax[3]));
        atomicMax(gmax, __float_as_uint(bm));
    }
}

__global__ __launch_bounds__(256) void cdm_pass2(
    float4* __restrict__ out, const unsigned int* __restrict__ gmax, int n4)
{
    const float inv = 1.0f / __uint_as_float(*gmax);
    const int i = blockIdx.x * 256 + threadIdx.x;
    if (i < n4) {
        float4 v = out[i];
        v.x *= inv; v.y *= inv; v.z *= inv; v.w *= inv;
        out[i] = v;
    }
}

extern "C" void kernel_launch(void* const* d_in, const int* in_sizes, int n_in,
                              void* d_out, int out_size, void* d_ws, size_t ws_size,
                              hipStream_t stream) {
    const float* contour = (const float*)d_in[0];
    float* out = (float*)d_out;
    unsigned int* gmax = (unsigned int*)d_ws;

    const int bn = in_sizes[0] / (KV * 2);            // 8
    const int npix = bn * MAP_SIZE * MAP_SIZE;        // 524288 == out_size

    hipMemsetAsync(gmax, 0, sizeof(unsigned int), stream);

    const int blocksPerImg = (MAP_SIZE * MAP_SIZE) / (256 * PPT);
    cdm_pass1<<<bn * blocksPerImg, 256, 0, stream>>>(contour, out, gmax);

    const int n4 = npix / 4;
    cdm_pass2<<<(n4 + 255) / 256, 256, 0, stream>>>((float4*)out, gmax, n4);
}